// Round 16
// baseline (41.601 us; speedup 1.0000x reference)
//
#include <hip/hip_runtime.h>
#include <math.h>

// ---------------------------------------------------------------------------
// B=32 queries [B,512] fp32 vs N=20000 keys [N,512] fp32.
// scores = Q K^T / sqrt(512); softmax over N; top-8; gather values rows.
// Output = [B*8 weights f32] ++ [B*8 * 10240 values f32].
//
// R16 = R15 with K2 split 2-ways per output row (512 blocks = 2/CU): the
// ~2us merge->rescore->sort prologue of one block overlaps the other's
// gather (R15 had 1 block/CU: zero TLP, serial prologue+gather ~5.4us).
// Each block gathers 20KB with a 5-deep load pipeline. Prologue is
// redundant (16x/row) but L2/L3-hot and bitwise-identical -> consistent.
//  K1 score_part: R15-proven VERBATIM (250 blocks x 80 keys, balanced).
//  K2 merge_gather: 512 blocks; (krk==0,half==0) writes weights.
// ---------------------------------------------------------------------------

#define TOPK 8
#define DKD 512
#define NEG  -1.0e30f
#define KPB  80          // keys per block in K1
#define TPB  5           // 16-key tiles per block

typedef __attribute__((ext_vector_type(8))) short short8;
typedef __attribute__((ext_vector_type(4))) float f32x4;

__device__ inline unsigned short f2bf(float x) {
    unsigned int u = __float_as_uint(x);
    u = (u + 0x7fffu + ((u >> 16) & 1u)) >> 16;   // RNE to bf16
    return (unsigned short)u;
}

// comparator everywhere: value desc, index asc (matches lax.top_k ties)
__device__ inline void wave_argmax(float& v, int& i) {
    #pragma unroll
    for (int off = 1; off < 64; off <<= 1) {
        float ov = __shfl_xor(v, off);
        int   oi = __shfl_xor(i, off);
        if (ov > v || (ov == v && oi < i)) { v = ov; i = oi; }
    }
}

// sorted-desc top-8 insert (strict > keeps earlier index on ties)
__device__ inline void top8_insert(float (&v)[8], int (&ji)[8], float x, int gi) {
    if (x > v[7]) {
        bool g[8];
        #pragma unroll
        for (int k = 0; k < 8; ++k) g[k] = (x > v[k]);
        #pragma unroll
        for (int k = 7; k >= 1; --k) {
            v[k]  = g[k] ? (g[k - 1] ? v[k - 1] : x)  : v[k];
            ji[k] = g[k] ? (g[k - 1] ? ji[k - 1] : gi) : ji[k];
        }
        v[0]  = g[0] ? x  : v[0];
        ji[0] = g[0] ? gi : ji[0];
    }
}

// ---- K1: balanced MFMA scores (80 keys/block) + per-row partials ----------
// R15-proven VERBATIM.
__global__ __launch_bounds__(256) void score_part_kernel(
    const float* __restrict__ q, const float* __restrict__ keys,
    float* __restrict__ pmg, float* __restrict__ psg,
    float* __restrict__ cvg, int* __restrict__ cig, int N, int NTB)
{
    const int tid  = threadIdx.x;
    const int lane = tid & 63;
    const int wid  = tid >> 6;
    const float scale = 0.04419417382415922f;   // 1/sqrt(512)

    __shared__ short qs[32][DKD + 8];   // bf16 q, +8 pad (2-way banks = free)
    __shared__ float S[32][KPB + 5];    // scores tile; stride 85 (gcd(85,32)=1)

    // ---- P0: q -> bf16 into LDS (64KB read, 1x per block) ----
    #pragma unroll
    for (int i = 0; i < 16; ++i) {
        const int idx = i * 256 + tid;          // 0..4095 float4s
        const int row = idx >> 7;               // 128 float4 per row
        const int c4  = idx & 127;
        float4 v = *reinterpret_cast<const float4*>(&q[row * DKD + c4 * 4]);
        ushort4 h;
        h.x = f2bf(v.x); h.y = f2bf(v.y); h.z = f2bf(v.z); h.w = f2bf(v.w);
        *reinterpret_cast<ushort4*>(&qs[row][c4 * 4]) = h;
    }
    __syncthreads();

    // ---- P1: 5 16-key tiles over 4 waves (wave 0 takes {0,4}) ----
    {
        const int col = lane & 15;
        const int kg  = lane >> 4;

        for (int t = wid; t < TPB; t += 4) {
            const int n0 = blockIdx.x * KPB + t * 16;

            f32x4 acc0 = {0.f, 0.f, 0.f, 0.f};
            f32x4 acc1 = {0.f, 0.f, 0.f, 0.f};

            int nrow = n0 + col;
            const bool valid = (nrow < N);
            if (!valid) nrow = N - 1;           // clamp loads
            const float* krow = keys + (size_t)nrow * DKD + kg * 8;
            const short* s0 = &qs[col][kg * 8];
            const short* s1 = &qs[col + 16][kg * 8];

            #pragma unroll 4
            for (int ks = 0; ks < 16; ++ks) {
                const int d = ks * 32;
                float4 ka = *reinterpret_cast<const float4*>(krow + d);
                float4 kb = *reinterpret_cast<const float4*>(krow + d + 4);
                short8 fh;
                fh[0] = (short)f2bf(ka.x); fh[1] = (short)f2bf(ka.y);
                fh[2] = (short)f2bf(ka.z); fh[3] = (short)f2bf(ka.w);
                fh[4] = (short)f2bf(kb.x); fh[5] = (short)f2bf(kb.y);
                fh[6] = (short)f2bf(kb.z); fh[7] = (short)f2bf(kb.w);
                short8 a0 = *reinterpret_cast<const short8*>(s0 + d);
                short8 a1 = *reinterpret_cast<const short8*>(s1 + d);
                acc0 = __builtin_amdgcn_mfma_f32_16x16x32_bf16(a0, fh, acc0, 0, 0, 0);
                acc1 = __builtin_amdgcn_mfma_f32_16x16x32_bf16(a1, fh, acc1, 0, 0, 0);
            }

            // D layout (m89-verified): col = lane&15, row = (lane>>4)*4 + reg
            #pragma unroll
            for (int j = 0; j < 4; ++j) {
                const int r = kg * 4 + j;
                S[r][t * 16 + col]      = valid ? acc0[j] * scale : NEG;
                S[r + 16][t * 16 + col] = valid ? acc1[j] * scale : NEG;
            }
        }
    }
    __syncthreads();

    // ---- P2: per-row partials: 8 threads/row x 10 cols each ----
    {
        const int r = tid >> 3;                 // row 0..31
        const int g = tid & 7;                  // 8-lane group position
        float m = NEG, s = 0.f;
        float v[8]; int ji[8];
        #pragma unroll
        for (int k = 0; k < 8; ++k) { v[k] = NEG; ji[k] = 0x7ffffffe; }

        #pragma unroll
        for (int e = 0; e < 10; ++e) {
            const int c  = g * 10 + e;
            const float x = S[r][c];
            const int  gi = blockIdx.x * KPB + c;
            if (x > -5e29f) {                   // skip invalid-key sentinels
                const float nm = fmaxf(m, x);
                s = s * __expf(m - nm) + __expf(x - nm);
                m = nm;
                top8_insert(v, ji, x, gi);
            }
        }

        // group (m,s) combine over 8 lanes
        #pragma unroll
        for (int off = 1; off < 8; off <<= 1) {
            float om = __shfl_xor(m, off), os = __shfl_xor(s, off);
            float M2 = fmaxf(m, om);
            s = s * __expf(m - M2) + os * __expf(om - M2);
            m = M2;
        }

        // group top-8 selection (8 rounds over 8 sorted lists)
        float sel_v[8]; int sel_i[8];
        #pragma unroll
        for (int rr = 0; rr < 8; ++rr) {
            float mv = v[0]; int mi = ji[0];
            #pragma unroll
            for (int off = 1; off < 8; off <<= 1) {
                float ov = __shfl_xor(mv, off);
                int   oi = __shfl_xor(mi, off);
                if (ov > mv || (ov == mv && oi < mi)) { mv = ov; mi = oi; }
            }
            if (v[0] == mv && ji[0] == mi) {    // I won: pop my head
                #pragma unroll
                for (int k = 0; k < 7; ++k) { v[k] = v[k + 1]; ji[k] = ji[k + 1]; }
                v[7] = NEG; ji[7] = 0x7ffffffe;
            }
            sel_v[rr] = mv; sel_i[rr] = mi;
        }

        if (g == 0) {
            const size_t base = (size_t)r * NTB + blockIdx.x;
            pmg[base] = m; psg[base] = s;
            #pragma unroll
            for (int k = 0; k < 8; ++k) {
                cvg[base * 8 + k] = sel_v[k];
                cig[base * 8 + k] = sel_i[k];
            }
        }
    }
}

// ---- K2: 512 blocks = 2 per output row: merge -> par. rescore -> gather ---
__global__ __launch_bounds__(256) void merge_gather_kernel(
    const float* __restrict__ pmg, const float* __restrict__ psg,
    const float* __restrict__ cvg, const int* __restrict__ cig,
    const float* __restrict__ q, const float* __restrict__ keys,
    const float* __restrict__ values,
    float* __restrict__ out_w, float* __restrict__ out_v, int NTB, int LDV)
{
    const int bk   = blockIdx.x >> 1;           // output row 0..255
    const int half = blockIdx.x & 1;            // gather half
    const int b    = bk >> 3;                   // query row
    const int krk  = bk & 7;                    // rank within top-8
    const int tid  = threadIdx.x;
    const int lane = tid & 63;
    const int wid  = tid >> 6;
    const float scale = 0.04419417382415922f;

    __shared__ float lm[4], ls[4], lcv[4][TOPK];
    __shared__ int   lci[4][TOPK];
    __shared__ float s_exv[12];
    __shared__ int   s_sid[12];

    // ---- thread-local: one partial each (NTB=250 <= 256: single round) ----
    float m = NEG, s = 0.f;
    float v[8]; int ji[8];
    #pragma unroll
    for (int k = 0; k < 8; ++k) { v[k] = NEG; ji[k] = 0x7ffffffe; }

    for (int tb = tid; tb < NTB; tb += 256) {
        const size_t base = (size_t)b * NTB + tb;
        const float pm_t = pmg[base], ps_t = psg[base];
        const float M2 = fmaxf(m, pm_t);
        s = s * __expf(m - M2) + ps_t * __expf(pm_t - M2);
        m = M2;
        #pragma unroll
        for (int k = 0; k < 8; ++k) {
            top8_insert(v, ji, cvg[base * 8 + k], cig[base * 8 + k]);
        }
    }

    // ---- wave-level (m,s) combine ----
    #pragma unroll
    for (int off = 1; off < 64; off <<= 1) {
        float om = __shfl_xor(m, off), os = __shfl_xor(s, off);
        float M2 = fmaxf(m, om);
        s = s * __expf(m - M2) + os * __expf(om - M2);
        m = M2;
    }

    // ---- wave-level top-8 merge: 8 selection rounds ----
    float selv = 0.f; int seli = 0;
    #pragma unroll
    for (int r = 0; r < TOPK; ++r) {
        float mv = v[0]; int mi = ji[0];
        wave_argmax(mv, mi);
        if (v[0] == mv && ji[0] == mi) {       // I won: pop my head
            #pragma unroll
            for (int k = 0; k < TOPK - 1; ++k) { v[k] = v[k + 1]; ji[k] = ji[k + 1]; }
            v[TOPK - 1] = NEG; ji[TOPK - 1] = 0x7ffffffe;
        }
        if (lane == r) { selv = mv; seli = mi; }
    }

    if (lane == 0) { lm[wid] = m; ls[wid] = s; }
    if (lane < TOPK) { lcv[wid][lane] = selv; lci[wid][lane] = seli; }
    __syncthreads();

    // ---- cross-wave combine (ALL waves, redundant -> everyone has M,S) ----
    float M = lm[0], S = ls[0];
    #pragma unroll
    for (int cc = 1; cc < 4; ++cc) {
        float M2 = fmaxf(M, lm[cc]);
        S = S * __expf(M - M2) + ls[cc] * __expf(lm[cc] - M2);
        M = M2;
    }

    // ---- 32 candidates -> approx top-12 (ALL waves, identical result) ----
    {
        float vv = (lane < 32) ? lcv[lane >> 3][lane & 7] : NEG;
        int   ii = (lane < 32) ? lci[lane >> 3][lane & 7] : 0x7ffffffe;
        int   si = 0x7ffffffe;
        #pragma unroll
        for (int r = 0; r < 12; ++r) {
            float mv = vv; int mi = ii;
            wave_argmax(mv, mi);
            if (vv == mv && ii == mi) vv = NEG;
            if (lane == r) si = mi;
        }

        // ---- wave wid rescores candidates 3*wid .. 3*wid+2 (fp32 exact,
        //      identical FP order across the row's 16 blocks) ----
        float4 qa = *reinterpret_cast<const float4*>(q + (size_t)b * DKD + lane * 8);
        float4 qb = *reinterpret_cast<const float4*>(q + (size_t)b * DKD + lane * 8 + 4);
        #pragma unroll
        for (int t = 0; t < 3; ++t) {
            const int r = wid * 3 + t;
            const int cand = __shfl(si, r);
            const float* kr = keys + (size_t)cand * DKD + lane * 8;
            float4 k1 = *reinterpret_cast<const float4*>(kr);
            float4 k2 = *reinterpret_cast<const float4*>(kr + 4);
            float p = qa.x * k1.x + qa.y * k1.y + qa.z * k1.z + qa.w * k1.w
                    + qb.x * k2.x + qb.y * k2.y + qb.z * k2.z + qb.w * k2.w;
            #pragma unroll
            for (int off = 1; off < 64; off <<= 1) p += __shfl_xor(p, off);
            if (lane == 0) { s_exv[r] = p * scale; s_sid[r] = cand; }
        }
    }
    __syncthreads();

    // ---- per-thread exact sort of the 12 (value desc, index asc) ----
    float ev[12]; int eid[12];
    #pragma unroll
    for (int k = 0; k < 12; ++k) { ev[k] = s_exv[k]; eid[k] = s_sid[k]; }
    #pragma unroll
    for (int a = 1; a < 12; ++a) {
        float xv = ev[a]; int xi = eid[a];
        int p = a - 1;
        while (p >= 0 && (ev[p] < xv || (ev[p] == xv && eid[p] > xi))) {
            ev[p + 1] = ev[p]; eid[p + 1] = eid[p]; --p;
        }
        ev[p + 1] = xv; eid[p + 1] = xi;
    }

    if (krk == 0 && half == 0 && tid < TOPK)
        out_w[b * TOPK + tid] = __expf(ev[tid] - M) / S;

    // ---- gather this half (20KB); all 5 loads in flight before stores ----
    const int id = eid[krk];                    // uniform across block
    const float4* src = reinterpret_cast<const float4*>(values + (size_t)id * LDV)
                        + half * 1280;
    float4*       dst = reinterpret_cast<float4*>(out_v + (size_t)bk * LDV)
                        + half * 1280;
    // half row = 1280 float4 = 5 * 256
    float4 buf[5];
    #pragma unroll
    for (int i = 0; i < 5; ++i) buf[i] = src[tid + i * 256];
    #pragma unroll
    for (int i = 0; i < 5; ++i) dst[tid + i * 256] = buf[i];
}

extern "C" void kernel_launch(void* const* d_in, const int* in_sizes, int n_in,
                              void* d_out, int out_size, void* d_ws, size_t ws_size,
                              hipStream_t stream) {
    const float* q      = (const float*)d_in[0];
    const float* keys   = (const float*)d_in[1];
    const float* values = (const float*)d_in[2];

    const int B   = in_sizes[0] / DKD;                 // 32
    const int N   = in_sizes[1] / DKD;                 // 20000
    const int LDV = (int)((long long)in_sizes[2] / N); // 10240
    const int NTB = (N + KPB - 1) / KPB;               // 250

    float* out   = (float*)d_out;
    float* out_w = out;
    float* out_v = out + (size_t)B * TOPK;

    char* wsb = (char*)d_ws;
    size_t off = 0;
    float* pmg = (float*)(wsb + off); off += (size_t)B * NTB * sizeof(float);
    float* psg = (float*)(wsb + off); off += (size_t)B * NTB * sizeof(float);
    float* cvg = (float*)(wsb + off); off += (size_t)B * NTB * 8 * sizeof(float);
    int*   cig = (int*)(wsb + off);   off += (size_t)B * NTB * 8 * sizeof(int);

    score_part_kernel<<<NTB, 256, 0, stream>>>(q, keys, pmg, psg, cvg, cig, N, NTB);
    merge_gather_kernel<<<B * TOPK * 2, 256, 0, stream>>>(
        pmg, psg, cvg, cig, q, keys, values, out_w, out_v, NTB, LDV);
}

// Round 17
// 40.225 us; speedup vs baseline: 1.0342x; 1.0342x over previous
//
#include <hip/hip_runtime.h>
#include <math.h>

// ---------------------------------------------------------------------------
// B=32 queries [B,512] fp32 vs N=20000 keys [N,512] fp32.
// scores = Q K^T / sqrt(512); softmax over N; top-8; gather values rows.
// Output = [B*8 weights f32] ++ [B*8 * 10240 values f32].
//
// FINAL (= R15, best measured: 40.3us, absmax 7.6e-6).
//  K1 score_part: 250 blocks x 80 keys (20000=250x80, perfectly balanced:
//     every CU streams the same bytes; R14's 313-block grid had 226/1024
//     wave-slots owning 2 tiles -> ~2x K1 time). q->bf16 LDS once/block;
//     bf16 MFMA screen (error ~3e-3 only used to SELECT candidates and for
//     the softmax denominator); per-row (m, sum-exp, top-8 of 80) partials.
//  K2 merge_gather: 256 blocks = one per output row. Merge 250 partials
//     (single round) -> cross-wave combine -> top-12 -> 4-wave-parallel
//     EXACT fp32 rescore (bitwise-identical across the row's 8 blocks ->
//     consistent selection; true top-8 \subset approx top-12 by ~80-sigma
//     margin) -> per-thread exact sort -> krk==0 writes weights; 10-deep
//     load-pipelined 40KB gather.
//
// Session law (R4/R7/R11/R12): on this stack, ANY in-kernel cross-block
// sync (coop grid.sync, atomic barrier, acquire-spin, even one ACQ_REL
// atomic per block) costs 80-300us. Only plain dependent kernel edges
// (~2us) are viable. Fixed graph-replay cost ~25us dominates the rest.
// ---------------------------------------------------------------------------

#define TOPK 8
#define DKD 512
#define NEG  -1.0e30f
#define KPB  80          // keys per block in K1
#define TPB  5           // 16-key tiles per block

typedef __attribute__((ext_vector_type(8))) short short8;
typedef __attribute__((ext_vector_type(4))) float f32x4;

__device__ inline unsigned short f2bf(float x) {
    unsigned int u = __float_as_uint(x);
    u = (u + 0x7fffu + ((u >> 16) & 1u)) >> 16;   // RNE to bf16
    return (unsigned short)u;
}

// comparator everywhere: value desc, index asc (matches lax.top_k ties)
__device__ inline void wave_argmax(float& v, int& i) {
    #pragma unroll
    for (int off = 1; off < 64; off <<= 1) {
        float ov = __shfl_xor(v, off);
        int   oi = __shfl_xor(i, off);
        if (ov > v || (ov == v && oi < i)) { v = ov; i = oi; }
    }
}

// sorted-desc top-8 insert (strict > keeps earlier index on ties)
__device__ inline void top8_insert(float (&v)[8], int (&ji)[8], float x, int gi) {
    if (x > v[7]) {
        bool g[8];
        #pragma unroll
        for (int k = 0; k < 8; ++k) g[k] = (x > v[k]);
        #pragma unroll
        for (int k = 7; k >= 1; --k) {
            v[k]  = g[k] ? (g[k - 1] ? v[k - 1] : x)  : v[k];
            ji[k] = g[k] ? (g[k - 1] ? ji[k - 1] : gi) : ji[k];
        }
        v[0]  = g[0] ? x  : v[0];
        ji[0] = g[0] ? gi : ji[0];
    }
}

// ---- K1: balanced MFMA scores (80 keys/block) + per-row partials ----------
__global__ __launch_bounds__(256) void score_part_kernel(
    const float* __restrict__ q, const float* __restrict__ keys,
    float* __restrict__ pmg, float* __restrict__ psg,
    float* __restrict__ cvg, int* __restrict__ cig, int N, int NTB)
{
    const int tid  = threadIdx.x;
    const int lane = tid & 63;
    const int wid  = tid >> 6;
    const float scale = 0.04419417382415922f;   // 1/sqrt(512)

    __shared__ short qs[32][DKD + 8];   // bf16 q, +8 pad (2-way banks = free)
    __shared__ float S[32][KPB + 5];    // scores tile; stride 85 (gcd(85,32)=1)

    // ---- P0: q -> bf16 into LDS (64KB read, 1x per block) ----
    #pragma unroll
    for (int i = 0; i < 16; ++i) {
        const int idx = i * 256 + tid;          // 0..4095 float4s
        const int row = idx >> 7;               // 128 float4 per row
        const int c4  = idx & 127;
        float4 v = *reinterpret_cast<const float4*>(&q[row * DKD + c4 * 4]);
        ushort4 h;
        h.x = f2bf(v.x); h.y = f2bf(v.y); h.z = f2bf(v.z); h.w = f2bf(v.w);
        *reinterpret_cast<ushort4*>(&qs[row][c4 * 4]) = h;
    }
    __syncthreads();

    // ---- P1: 5 16-key tiles over 4 waves (wave 0 takes {0,4}) ----
    {
        const int col = lane & 15;
        const int kg  = lane >> 4;

        for (int t = wid; t < TPB; t += 4) {
            const int n0 = blockIdx.x * KPB + t * 16;

            f32x4 acc0 = {0.f, 0.f, 0.f, 0.f};
            f32x4 acc1 = {0.f, 0.f, 0.f, 0.f};

            int nrow = n0 + col;
            const bool valid = (nrow < N);
            if (!valid) nrow = N - 1;           // clamp loads
            const float* krow = keys + (size_t)nrow * DKD + kg * 8;
            const short* s0 = &qs[col][kg * 8];
            const short* s1 = &qs[col + 16][kg * 8];

            #pragma unroll 4
            for (int ks = 0; ks < 16; ++ks) {
                const int d = ks * 32;
                float4 ka = *reinterpret_cast<const float4*>(krow + d);
                float4 kb = *reinterpret_cast<const float4*>(krow + d + 4);
                short8 fh;
                fh[0] = (short)f2bf(ka.x); fh[1] = (short)f2bf(ka.y);
                fh[2] = (short)f2bf(ka.z); fh[3] = (short)f2bf(ka.w);
                fh[4] = (short)f2bf(kb.x); fh[5] = (short)f2bf(kb.y);
                fh[6] = (short)f2bf(kb.z); fh[7] = (short)f2bf(kb.w);
                short8 a0 = *reinterpret_cast<const short8*>(s0 + d);
                short8 a1 = *reinterpret_cast<const short8*>(s1 + d);
                acc0 = __builtin_amdgcn_mfma_f32_16x16x32_bf16(a0, fh, acc0, 0, 0, 0);
                acc1 = __builtin_amdgcn_mfma_f32_16x16x32_bf16(a1, fh, acc1, 0, 0, 0);
            }

            // D layout (m89-verified): col = lane&15, row = (lane>>4)*4 + reg
            #pragma unroll
            for (int j = 0; j < 4; ++j) {
                const int r = kg * 4 + j;
                S[r][t * 16 + col]      = valid ? acc0[j] * scale : NEG;
                S[r + 16][t * 16 + col] = valid ? acc1[j] * scale : NEG;
            }
        }
    }
    __syncthreads();

    // ---- P2: per-row partials: 8 threads/row x 10 cols each ----
    {
        const int r = tid >> 3;                 // row 0..31
        const int g = tid & 7;                  // 8-lane group position
        float m = NEG, s = 0.f;
        float v[8]; int ji[8];
        #pragma unroll
        for (int k = 0; k < 8; ++k) { v[k] = NEG; ji[k] = 0x7ffffffe; }

        #pragma unroll
        for (int e = 0; e < 10; ++e) {
            const int c  = g * 10 + e;
            const float x = S[r][c];
            const int  gi = blockIdx.x * KPB + c;
            if (x > -5e29f) {                   // skip invalid-key sentinels
                const float nm = fmaxf(m, x);
                s = s * __expf(m - nm) + __expf(x - nm);
                m = nm;
                top8_insert(v, ji, x, gi);
            }
        }

        // group (m,s) combine over 8 lanes
        #pragma unroll
        for (int off = 1; off < 8; off <<= 1) {
            float om = __shfl_xor(m, off), os = __shfl_xor(s, off);
            float M2 = fmaxf(m, om);
            s = s * __expf(m - M2) + os * __expf(om - M2);
            m = M2;
        }

        // group top-8 selection (8 rounds over 8 sorted lists)
        float sel_v[8]; int sel_i[8];
        #pragma unroll
        for (int rr = 0; rr < 8; ++rr) {
            float mv = v[0]; int mi = ji[0];
            #pragma unroll
            for (int off = 1; off < 8; off <<= 1) {
                float ov = __shfl_xor(mv, off);
                int   oi = __shfl_xor(mi, off);
                if (ov > mv || (ov == mv && oi < mi)) { mv = ov; mi = oi; }
            }
            if (v[0] == mv && ji[0] == mi) {    // I won: pop my head
                #pragma unroll
                for (int k = 0; k < 7; ++k) { v[k] = v[k + 1]; ji[k] = ji[k + 1]; }
                v[7] = NEG; ji[7] = 0x7ffffffe;
            }
            sel_v[rr] = mv; sel_i[rr] = mi;
        }

        if (g == 0) {
            const size_t base = (size_t)r * NTB + blockIdx.x;
            pmg[base] = m; psg[base] = s;
            #pragma unroll
            for (int k = 0; k < 8; ++k) {
                cvg[base * 8 + k] = sel_v[k];
                cig[base * 8 + k] = sel_i[k];
            }
        }
    }
}

// ---- K2: 256 blocks = one per output row: merge -> par. rescore -> gather -
__global__ __launch_bounds__(256) void merge_gather_kernel(
    const float* __restrict__ pmg, const float* __restrict__ psg,
    const float* __restrict__ cvg, const int* __restrict__ cig,
    const float* __restrict__ q, const float* __restrict__ keys,
    const float* __restrict__ values,
    float* __restrict__ out_w, float* __restrict__ out_v, int NTB, int LDV)
{
    const int bk   = blockIdx.x;                // output row 0..255
    const int b    = bk >> 3;                   // query row
    const int krk  = bk & 7;                    // rank within top-8
    const int tid  = threadIdx.x;
    const int lane = tid & 63;
    const int wid  = tid >> 6;
    const float scale = 0.04419417382415922f;

    __shared__ float lm[4], ls[4], lcv[4][TOPK];
    __shared__ int   lci[4][TOPK];
    __shared__ float s_exv[12];
    __shared__ int   s_sid[12];

    // ---- thread-local: one partial each (NTB=250 <= 256: single round) ----
    float m = NEG, s = 0.f;
    float v[8]; int ji[8];
    #pragma unroll
    for (int k = 0; k < 8; ++k) { v[k] = NEG; ji[k] = 0x7ffffffe; }

    for (int tb = tid; tb < NTB; tb += 256) {
        const size_t base = (size_t)b * NTB + tb;
        const float pm_t = pmg[base], ps_t = psg[base];
        const float M2 = fmaxf(m, pm_t);
        s = s * __expf(m - M2) + ps_t * __expf(pm_t - M2);
        m = M2;
        #pragma unroll
        for (int k = 0; k < 8; ++k) {
            top8_insert(v, ji, cvg[base * 8 + k], cig[base * 8 + k]);
        }
    }

    // ---- wave-level (m,s) combine ----
    #pragma unroll
    for (int off = 1; off < 64; off <<= 1) {
        float om = __shfl_xor(m, off), os = __shfl_xor(s, off);
        float M2 = fmaxf(m, om);
        s = s * __expf(m - M2) + os * __expf(om - M2);
        m = M2;
    }

    // ---- wave-level top-8 merge: 8 selection rounds ----
    float selv = 0.f; int seli = 0;
    #pragma unroll
    for (int r = 0; r < TOPK; ++r) {
        float mv = v[0]; int mi = ji[0];
        wave_argmax(mv, mi);
        if (v[0] == mv && ji[0] == mi) {       // I won: pop my head
            #pragma unroll
            for (int k = 0; k < TOPK - 1; ++k) { v[k] = v[k + 1]; ji[k] = ji[k + 1]; }
            v[TOPK - 1] = NEG; ji[TOPK - 1] = 0x7ffffffe;
        }
        if (lane == r) { selv = mv; seli = mi; }
    }

    if (lane == 0) { lm[wid] = m; ls[wid] = s; }
    if (lane < TOPK) { lcv[wid][lane] = selv; lci[wid][lane] = seli; }
    __syncthreads();

    // ---- cross-wave combine (ALL waves, redundant -> everyone has M,S) ----
    float M = lm[0], S = ls[0];
    #pragma unroll
    for (int cc = 1; cc < 4; ++cc) {
        float M2 = fmaxf(M, lm[cc]);
        S = S * __expf(M - M2) + ls[cc] * __expf(lm[cc] - M2);
        M = M2;
    }

    // ---- 32 candidates -> approx top-12 (ALL waves, identical result) ----
    {
        float vv = (lane < 32) ? lcv[lane >> 3][lane & 7] : NEG;
        int   ii = (lane < 32) ? lci[lane >> 3][lane & 7] : 0x7ffffffe;
        int   si = 0x7ffffffe;
        #pragma unroll
        for (int r = 0; r < 12; ++r) {
            float mv = vv; int mi = ii;
            wave_argmax(mv, mi);
            if (vv == mv && ii == mi) vv = NEG;
            if (lane == r) si = mi;
        }

        // ---- wave wid rescores candidates 3*wid .. 3*wid+2 (fp32 exact,
        //      identical FP order across the row's 8 blocks) ----
        float4 qa = *reinterpret_cast<const float4*>(q + (size_t)b * DKD + lane * 8);
        float4 qb = *reinterpret_cast<const float4*>(q + (size_t)b * DKD + lane * 8 + 4);
        #pragma unroll
        for (int t = 0; t < 3; ++t) {
            const int r = wid * 3 + t;
            const int cand = __shfl(si, r);
            const float* kr = keys + (size_t)cand * DKD + lane * 8;
            float4 k1 = *reinterpret_cast<const float4*>(kr);
            float4 k2 = *reinterpret_cast<const float4*>(kr + 4);
            float p = qa.x * k1.x + qa.y * k1.y + qa.z * k1.z + qa.w * k1.w
                    + qb.x * k2.x + qb.y * k2.y + qb.z * k2.z + qb.w * k2.w;
            #pragma unroll
            for (int off = 1; off < 64; off <<= 1) p += __shfl_xor(p, off);
            if (lane == 0) { s_exv[r] = p * scale; s_sid[r] = cand; }
        }
    }
    __syncthreads();

    // ---- per-thread exact sort of the 12 (value desc, index asc) ----
    float ev[12]; int eid[12];
    #pragma unroll
    for (int k = 0; k < 12; ++k) { ev[k] = s_exv[k]; eid[k] = s_sid[k]; }
    #pragma unroll
    for (int a = 1; a < 12; ++a) {
        float xv = ev[a]; int xi = eid[a];
        int p = a - 1;
        while (p >= 0 && (ev[p] < xv || (ev[p] == xv && eid[p] > xi))) {
            ev[p + 1] = ev[p]; eid[p + 1] = eid[p]; --p;
        }
        ev[p + 1] = xv; eid[p + 1] = xi;
    }

    if (krk == 0 && tid < TOPK)
        out_w[b * TOPK + tid] = __expf(ev[tid] - M) / S;

    // ---- gather the full 40KB row; all 10 loads in flight before stores ----
    const int id = eid[krk];                    // uniform across block
    const float4* src = reinterpret_cast<const float4*>(values + (size_t)id * LDV);
    float4*       dst = reinterpret_cast<float4*>(out_v + (size_t)bk * LDV);
    // LDV/4 = 2560 = 10 * 256
    float4 buf[10];
    #pragma unroll
    for (int i = 0; i < 10; ++i) buf[i] = src[tid + i * 256];
    #pragma unroll
    for (int i = 0; i < 10; ++i) dst[tid + i * 256] = buf[i];
}

extern "C" void kernel_launch(void* const* d_in, const int* in_sizes, int n_in,
                              void* d_out, int out_size, void* d_ws, size_t ws_size,
                              hipStream_t stream) {
    const float* q      = (const float*)d_in[0];
    const float* keys   = (const float*)d_in[1];
    const float* values = (const float*)d_in[2];

    const int B   = in_sizes[0] / DKD;                 // 32
    const int N   = in_sizes[1] / DKD;                 // 20000
    const int LDV = (int)((long long)in_sizes[2] / N); // 10240
    const int NTB = (N + KPB - 1) / KPB;               // 250

    float* out   = (float*)d_out;
    float* out_w = out;
    float* out_v = out + (size_t)B * TOPK;

    char* wsb = (char*)d_ws;
    size_t off = 0;
    float* pmg = (float*)(wsb + off); off += (size_t)B * NTB * sizeof(float);
    float* psg = (float*)(wsb + off); off += (size_t)B * NTB * sizeof(float);
    float* cvg = (float*)(wsb + off); off += (size_t)B * NTB * 8 * sizeof(float);
    int*   cig = (int*)(wsb + off);   off += (size_t)B * NTB * 8 * sizeof(int);

    score_part_kernel<<<NTB, 256, 0, stream>>>(q, keys, pmg, psg, cvg, cig, N, NTB);
    merge_gather_kernel<<<B * TOPK, 256, 0, stream>>>(
        pmg, psg, cvg, cig, q, keys, values, out_w, out_v, NTB, LDV);
}